// Round 9
// baseline (103.175 us; speedup 1.0000x reference)
//
#include <hip/hip_runtime.h>
#include <math.h>

// GP_conv2D: N=8, IH=IW=32, IC=8, OC=16, 3x3 s1 p1, P=5, I_DIM=72
#define OC_N   16
#define I_DIM  72
#define PN     5
#define NEU    (OC_N * I_DIM)   // 1152
#define NF     32               // floats per neuron record (128 B)
#define RTOT   8192             // N * OH * OW
#define OUT_HALF (RTOT * OC_N)  // 131072
#define LOG2E  1.4426950408889634f
#define RLOG2E 0.6931471805599453f

#if __has_builtin(__builtin_amdgcn_rcpf)
#define RCPF(x) __builtin_amdgcn_rcpf(x)
#else
#define RCPF(x) (1.0f / (x))
#endif
#if __has_builtin(__builtin_amdgcn_exp2f)
#define EXP2F(x) __builtin_amdgcn_exp2f(x)
#else
#define EXP2F(x) exp2f(x)
#endif
#if __has_builtin(__builtin_amdgcn_logf)
#define LOG2F(x) __builtin_amdgcn_logf(x)
#else
#define LOG2F(x) log2f(x)
#endif
#if __has_builtin(__builtin_amdgcn_rsqf)
#define RSQF(x) __builtin_amdgcn_rsqf(x)
#else
#define RSQF(x) rsqrtf(x)
#endif

// Neuron record layout (32 floats):
// [0]=l2  [1]=l  [2..6]=z[p]  [7..11]=alpha[p]
// [12..16]=Kinv diag  [17..26]=2*Kinv offdiag (01,02,03,04,12,13,14,23,24,34)

__global__ __launch_bounds__(256) void gp_prep_kernel(
    const float* __restrict__ zin, const float* __restrict__ hin,
    const float* __restrict__ rlin, float* __restrict__ nr) {
  int idx = blockIdx.x * blockDim.x + threadIdx.x;
  if (idx >= NEU) return;
  float x  = rlin[idx];
  float t  = EXP2F(-fabsf(x) * LOG2E);
  float sp = fmaxf(x, 0.0f) + LOG2F(1.0f + t) * RLOG2E;
  float l2 = sp * sp;
  float cexp = -0.5f * LOG2E * RCPF(l2);

  float zz[PN], hh[PN];
#pragma unroll
  for (int p = 0; p < PN; ++p) {
    zz[p] = zin[idx * PN + p];
    hh[p] = hin[idx * PN + p];
  }
  float A[PN][PN], B[PN][PN];
#pragma unroll
  for (int p = 0; p < PN; ++p) {
#pragma unroll
    for (int q = 0; q < PN; ++q) {
      float dz = zz[p] - zz[q];
      A[p][q] = EXP2F(cexp * dz * dz);
      B[p][q] = (p == q) ? 1.0f : 0.0f;
    }
  }
#pragma unroll
  for (int p = 0; p < PN; ++p) A[p][p] += 1e-4f;

#pragma unroll
  for (int cc = 0; cc < PN; ++cc) {
    float pivinv = RCPF(A[cc][cc]);
#pragma unroll
    for (int j = 0; j < PN; ++j) { A[cc][j] *= pivinv; B[cc][j] *= pivinv; }
#pragma unroll
    for (int r = 0; r < PN; ++r) {
      if (r == cc) continue;
      float f = A[r][cc];
#pragma unroll
      for (int j = 0; j < PN; ++j) { A[r][j] -= f * A[cc][j]; B[r][j] -= f * B[cc][j]; }
    }
  }
  float alpha[PN];
#pragma unroll
  for (int p = 0; p < PN; ++p) {
    float s = 0.0f;
#pragma unroll
    for (int q = 0; q < PN; ++q) s += B[p][q] * hh[q];
    alpha[p] = s;
  }
  float* o = nr + idx * NF;
  o[0] = l2;
  o[1] = sp;                       // l (for rsq-based coef)
#pragma unroll
  for (int p = 0; p < PN; ++p) {
    o[2 + p]  = zz[p];
    o[7 + p]  = alpha[p];
    o[12 + p] = B[p][p];
  }
  int j = 17;
#pragma unroll
  for (int p = 0; p < PN; ++p)
#pragma unroll
    for (int q = p + 1; q < PN; ++q) o[j++] = 2.0f * B[p][q];
  o[27] = o[28] = o[29] = o[30] = o[31] = 0.0f;
}

// Persistent-style main: wave = one (o, 32-row group); loops k=0..8 internally
// with params double-buffered in VGPRs (prefetch k+1 during compute of k) and
// mean/qkq accumulated across k in registers. End: c-butterfly + direct store.
// 4096 waves = 1024 blocks x 256 thr. 2 dispatches total, no partial buffers.
__global__ __launch_bounds__(256, 3) void gp_main_kernel(
    const float* __restrict__ xm, const float* __restrict__ xv,
    const float* __restrict__ nr, float* __restrict__ out) {
  const int tx    = threadIdx.x;
  const int lane  = tx & 63;
  const int wv    = tx >> 6;                     // wave in block 0..3
  const int gwave = blockIdx.x * 4 + wv;         // 0..4095
  const int rlo   = lane >> 3;                   // 0..7
  const int c     = lane & 7;                    // input channel
  const int o     = gwave >> 8;                  // 0..15
  const int rg    = gwave & 255;                 // 32-row group
  const int rbase = rg * 32;                     // rows rbase..rbase+31
  // all 32 rows share one image row: (n, oh), ow = 0..31
  const int n   = rbase >> 10;
  const int oh  = (rbase & 1023) >> 5;

  const float* base = nr + (o * I_DIM + c * 9) * NF;   // record(o, c*9+k)

  float macc[4] = {0.f, 0.f, 0.f, 0.f};
  float qacc[4] = {0.f, 0.f, 0.f, 0.f};

  float P[28];
  {
    const float4* r4 = (const float4*)base;            // k = 0
#pragma unroll
    for (int j = 0; j < 7; ++j) ((float4*)P)[j] = r4[j];
  }

#pragma unroll 1
  for (int k = 0; k < 9; ++k) {
    float Pn[28];
    if (k < 8) {                                       // prefetch k+1
      const float4* r4 = (const float4*)(base + (k + 1) * NF);
#pragma unroll
      for (int j = 0; j < 7; ++j) ((float4*)Pn)[j] = r4[j];
    }

    const int kh = (k * 11) >> 5;                      // k/3 for k in 0..8
    const int kw = k - 3 * kh;
    const int ih = oh + kh - 1;                        // scalar
    const bool vh = ((unsigned)ih < 32u);
    const int ihc = ih < 0 ? 0 : (ih > 31 ? 31 : ih);
    const int rowbase = ((n * 32 + ihc) * 32) * 8 + c; // per-lane
    const int wo = rlo + kw - 1;                       // per-lane w offset

    const float l2 = P[0];
    const float l1 = P[1];

#pragma unroll
    for (int it = 0; it < 4; ++it) {
      const int iw = it * 8 + wo;                      // [-1, 32]
      const bool valid = vh & ((unsigned)iw < 32u);
      const int iwc = iw < 0 ? 0 : (iw > 31 ? 31 : iw);
      float m = xm[rowbase + iwc * 8];
      float s = xv[rowbase + iwc * 8];
      m = valid ? m : 0.0f;
      s = valid ? s : 0.0f;

      const float d     = l2 + s;
      const float irs   = RSQF(d);                     // 1/sqrt(d)
      const float coef  = l1 * irs;                    // sqrt(l2/d)
      const float coef2 = coef * coef;                 // l2/d
      const float el    = -0.72134752044f * (irs * irs); // -0.5*log2e/d
      const float d0 = m - P[2];
      const float d1 = m - P[3];
      const float d2 = m - P[4];
      const float d3 = m - P[5];
      const float d4 = m - P[6];
      const float u0 = EXP2F(el * d0 * d0);
      const float u1 = EXP2F(el * d1 * d1);
      const float u2 = EXP2F(el * d2 * d2);
      const float u3 = EXP2F(el * d3 * d3);
      const float u4 = EXP2F(el * d4 * d4);
      const float dotA =
          fmaf(u0, P[7], fmaf(u1, P[8], fmaf(u2, P[9], fmaf(u3, P[10], u4 * P[11]))));
      const float t0 = fmaf(P[12], u0, fmaf(P[17], u1, fmaf(P[18], u2, fmaf(P[19], u3, P[20] * u4))));
      const float t1 = fmaf(P[13], u1, fmaf(P[21], u2, fmaf(P[22], u3, P[23] * u4)));
      const float t2 = fmaf(P[14], u2, fmaf(P[24], u3, P[25] * u4));
      const float t3 = fmaf(P[15], u3, P[26] * u4);
      const float t4 = P[16] * u4;
      const float quad =
          fmaf(u0, t0, fmaf(u1, t1, fmaf(u2, t2, fmaf(u3, t3, u4 * t4))));
      macc[it] = fmaf(coef, dotA, macc[it]);
      qacc[it] = fmaf(coef2, quad, qacc[it]);
    }

    if (k < 8) {
#pragma unroll
      for (int j = 0; j < 28; ++j) P[j] = Pn[j];
    }
  }

  // reduce over c (low 3 lane bits) and store final outputs
#pragma unroll
  for (int it = 0; it < 4; ++it) {
    float mv = macc[it], qv = qacc[it];
    mv += __shfl_xor(mv, 1); qv += __shfl_xor(qv, 1);
    mv += __shfl_xor(mv, 2); qv += __shfl_xor(qv, 2);
    mv += __shfl_xor(mv, 4); qv += __shfl_xor(qv, 4);
    if (c == 0) {
      const int r = rbase + it * 8 + rlo;
      out[r * OC_N + o] = mv;
      out[OUT_HALF + r * OC_N + o] = fmaxf(72.0f - qv, 1e-6f);
    }
  }
}

extern "C" void kernel_launch(void* const* d_in, const int* in_sizes, int n_in,
                              void* d_out, int out_size, void* d_ws, size_t ws_size,
                              hipStream_t stream) {
  const float* xm = (const float*)d_in[0];   // x_mean [8,32,32,8]
  const float* xv = (const float*)d_in[1];   // x_var  [8,32,32,8]
  const float* z  = (const float*)d_in[2];   // [16,72,5]
  const float* h  = (const float*)d_in[3];   // [16,72,5]
  const float* rl = (const float*)d_in[4];   // [16,72]
  float* out = (float*)d_out;                // mean(131072) ++ var(131072)
  float* nr  = (float*)d_ws;                 // 147456 B

  gp_prep_kernel<<<dim3((NEU + 255) / 256), dim3(256), 0, stream>>>(z, h, rl, nr);

  dim3 grid(1024);                           // 4096 waves = 16 o x 256 groups
  gp_main_kernel<<<grid, dim3(256), 0, stream>>>(xm, xv, nr, out);
}

// Round 10
// 95.833 us; speedup vs baseline: 1.0766x; 1.0766x over previous
//
#include <hip/hip_runtime.h>
#include <math.h>

// GP_conv2D: N=8, IH=IW=32, IC=8, OC=16, 3x3 s1 p1, P=5, I_DIM=72
#define OC_N   16
#define I_DIM  72
#define PN     5
#define NEU    (OC_N * I_DIM)   // 1152
#define NF     32               // floats per neuron record (128 B)
#define RTOT   8192             // N * OH * OW
#define OUT_HALF (RTOT * OC_N)  // 131072
#define LOG2E  1.4426950408889634f
#define RLOG2E 0.6931471805599453f

#if __has_builtin(__builtin_amdgcn_rcpf)
#define RCPF(x) __builtin_amdgcn_rcpf(x)
#else
#define RCPF(x) (1.0f / (x))
#endif
#if __has_builtin(__builtin_amdgcn_exp2f)
#define EXP2F(x) __builtin_amdgcn_exp2f(x)
#else
#define EXP2F(x) exp2f(x)
#endif
#if __has_builtin(__builtin_amdgcn_logf)
#define LOG2F(x) __builtin_amdgcn_logf(x)
#else
#define LOG2F(x) log2f(x)
#endif
#if __has_builtin(__builtin_amdgcn_rsqf)
#define RSQF(x) __builtin_amdgcn_rsqf(x)
#else
#define RSQF(x) rsqrtf(x)
#endif

// Neuron record layout (32 floats):
// [0]=l2  [1]=l  [2..6]=z[p]  [7..11]=alpha[p]
// [12..16]=Kinv diag  [17..26]=2*Kinv offdiag (01,02,03,04,12,13,14,23,24,34)

__global__ __launch_bounds__(256) void gp_prep_kernel(
    const float* __restrict__ zin, const float* __restrict__ hin,
    const float* __restrict__ rlin, float* __restrict__ nr) {
  int idx = blockIdx.x * blockDim.x + threadIdx.x;
  if (idx >= NEU) return;
  float x  = rlin[idx];
  float t  = EXP2F(-fabsf(x) * LOG2E);
  float sp = fmaxf(x, 0.0f) + LOG2F(1.0f + t) * RLOG2E;
  float l2 = sp * sp;
  float cexp = -0.5f * LOG2E * RCPF(l2);

  float zz[PN], hh[PN];
#pragma unroll
  for (int p = 0; p < PN; ++p) {
    zz[p] = zin[idx * PN + p];
    hh[p] = hin[idx * PN + p];
  }
  float A[PN][PN], B[PN][PN];
#pragma unroll
  for (int p = 0; p < PN; ++p) {
#pragma unroll
    for (int q = 0; q < PN; ++q) {
      float dz = zz[p] - zz[q];
      A[p][q] = EXP2F(cexp * dz * dz);
      B[p][q] = (p == q) ? 1.0f : 0.0f;
    }
  }
#pragma unroll
  for (int p = 0; p < PN; ++p) A[p][p] += 1e-4f;

#pragma unroll
  for (int cc = 0; cc < PN; ++cc) {
    float pivinv = RCPF(A[cc][cc]);
#pragma unroll
    for (int j = 0; j < PN; ++j) { A[cc][j] *= pivinv; B[cc][j] *= pivinv; }
#pragma unroll
    for (int r = 0; r < PN; ++r) {
      if (r == cc) continue;
      float f = A[r][cc];
#pragma unroll
      for (int j = 0; j < PN; ++j) { A[r][j] -= f * A[cc][j]; B[r][j] -= f * B[cc][j]; }
    }
  }
  float alpha[PN];
#pragma unroll
  for (int p = 0; p < PN; ++p) {
    float s = 0.0f;
#pragma unroll
    for (int q = 0; q < PN; ++q) s += B[p][q] * hh[q];
    alpha[p] = s;
  }
  float* o = nr + idx * NF;
  o[0] = l2;
  o[1] = sp;                       // l (for rsq-based coef)
#pragma unroll
  for (int p = 0; p < PN; ++p) {
    o[2 + p]  = zz[p];
    o[7 + p]  = alpha[p];
    o[12 + p] = B[p][p];
  }
  int j = 17;
#pragma unroll
  for (int p = 0; p < PN; ++p)
#pragma unroll
    for (int q = p + 1; q < PN; ++q) o[j++] = 2.0f * B[p][q];
  o[27] = o[28] = o[29] = o[30] = o[31] = 0.0f;
}

// Fused main with LDS input staging.
// Block = (64 rows, 9 tap-waves) for one o. The 64 rows are 2 image rows
// (oh0, oh0+1) of one n; taps need ih in [oh0-1, oh0+2] -> 4 image rows.
// Staged into LDS as [2 arrays][4 rows][34 cols][8 ch] with zero pads at
// col 0 and 33 (iw=-1/32) and zero rows for ih OOB -> inner loop has NO
// global loads and NO validity masks: 2 ds_reads + pure VALU.
__global__ __launch_bounds__(576, 2) void gp_fused_kernel(
    const float* __restrict__ xm, const float* __restrict__ xv,
    const float* __restrict__ nr, float* __restrict__ out) {
  __shared__ float stage[2][4][34][8];   // 8704 B
  __shared__ float2 red[9][64];          // 4608 B

  const int tx   = threadIdx.x;          // 0..63
  const int rlo  = tx >> 3;              // 0..7
  const int c    = tx & 7;               // channel
  const int k    = __builtin_amdgcn_readfirstlane(threadIdx.y);  // tap 0..8
  const int kh   = k / 3;
  const int kw   = k - 3 * kh;
  const int o    = blockIdx.y;
  const int rbase = blockIdx.x * 64;     // 64 rows, same n, oh0 & oh0+1
  const int n    = rbase >> 10;
  const int oh0  = (rbase & 1023) >> 5;

  // ---- cooperative staging: 2176 floats, coalesced, zero-padded ----
  {
    const int tid = threadIdx.y * 64 + tx;          // 0..575
    float* flat = (float*)stage;
    for (int idx = tid; idx < 2176; idx += 576) {
      const int arr = idx / 1088;                   // 0=m, 1=s
      const int rem = idx - arr * 1088;
      const int j   = rem / 272;                    // staged row 0..3
      const int f   = rem - j * 272;                // 0..271
      const int pos = f >> 3;                       // 0..33
      const int cc  = f & 7;
      const int iw  = pos - 1;                      // -1..32
      const int ih  = oh0 - 1 + j;                  // may be OOB
      const bool valid = ((unsigned)ih < 32u) & ((unsigned)iw < 32u);
      const int ihc = ih < 0 ? 0 : (ih > 31 ? 31 : ih);
      const int iwc = iw < 0 ? 0 : (iw > 31 ? 31 : iw);
      const float* g = arr ? xv : xm;
      float v = g[((n * 32 + ihc) * 32 + iwc) * 8 + cc];
      flat[idx] = valid ? v : 0.0f;
    }
  }

  // ---- per-lane params, VGPR-resident ----
  float P[28];
  {
    const float4* rec4 = (const float4*)(nr + (o * I_DIM + (c * 9 + k)) * NF);
#pragma unroll
    for (int j = 0; j < 7; ++j) ((float4*)P)[j] = rec4[j];
  }
  const float l2 = P[0];
  const float l1 = P[1];

  __syncthreads();

  const int ih_l = kh;                   // + oh_l below (stage row = oh_l+kh)
#pragma unroll
  for (int it = 0; it < 8; ++it) {
    const int oh_l = it >> 2;            // 0 or 1
    const int ow0  = (it & 3) << 3;      // 0,8,16,24
    // stage[arr][oh_l+kh][ow0+kw+rlo][c] ; per-lane addr = base + lane -> conflict-free
    const float m = stage[0][oh_l + ih_l][ow0 + kw + rlo][c];
    const float s = stage[1][oh_l + ih_l][ow0 + kw + rlo][c];

    const float d     = l2 + s;
    const float irs   = RSQF(d);                       // 1/sqrt(d)
    const float coef  = l1 * irs;                      // sqrt(l2/d)
    const float coef2 = coef * coef;                   // l2/d
    const float el    = -0.72134752044f * (irs * irs); // -0.5*log2e/d
    const float d0 = m - P[2];
    const float d1 = m - P[3];
    const float d2 = m - P[4];
    const float d3 = m - P[5];
    const float d4 = m - P[6];
    const float u0 = EXP2F(el * d0 * d0);
    const float u1 = EXP2F(el * d1 * d1);
    const float u2 = EXP2F(el * d2 * d2);
    const float u3 = EXP2F(el * d3 * d3);
    const float u4 = EXP2F(el * d4 * d4);
    const float dotA =
        fmaf(u0, P[7], fmaf(u1, P[8], fmaf(u2, P[9], fmaf(u3, P[10], u4 * P[11]))));
    const float t0 = fmaf(P[12], u0, fmaf(P[17], u1, fmaf(P[18], u2, fmaf(P[19], u3, P[20] * u4))));
    const float t1 = fmaf(P[13], u1, fmaf(P[21], u2, fmaf(P[22], u3, P[23] * u4)));
    const float t2 = fmaf(P[14], u2, fmaf(P[24], u3, P[25] * u4));
    const float t3 = fmaf(P[15], u3, P[26] * u4);
    const float t4 = P[16] * u4;
    const float quad =
        fmaf(u0, t0, fmaf(u1, t1, fmaf(u2, t2, fmaf(u3, t3, u4 * t4))));
    float mean = coef * dotA;
    float qkq  = coef2 * quad;

    // reduce over c (low 3 lane bits)
    mean += __shfl_xor(mean, 1); qkq += __shfl_xor(qkq, 1);
    mean += __shfl_xor(mean, 2); qkq += __shfl_xor(qkq, 2);
    mean += __shfl_xor(mean, 4); qkq += __shfl_xor(qkq, 4);
    if (c == 0) red[k][it * 8 + rlo] = make_float2(mean, qkq);
  }

  __syncthreads();
  if (threadIdx.y == 0) {
    float msum = 0.0f, qsum = 0.0f;
#pragma unroll
    for (int s = 0; s < 9; ++s) {
      const float2 v = red[s][tx];
      msum += v.x;
      qsum += v.y;
    }
    const int i = (rbase + tx) * OC_N + o;
    out[i] = msum;
    out[OUT_HALF + i] = fmaxf(72.0f - qsum, 1e-6f);
  }
}

extern "C" void kernel_launch(void* const* d_in, const int* in_sizes, int n_in,
                              void* d_out, int out_size, void* d_ws, size_t ws_size,
                              hipStream_t stream) {
  const float* xm = (const float*)d_in[0];   // x_mean [8,32,32,8]
  const float* xv = (const float*)d_in[1];   // x_var  [8,32,32,8]
  const float* z  = (const float*)d_in[2];   // [16,72,5]
  const float* h  = (const float*)d_in[3];   // [16,72,5]
  const float* rl = (const float*)d_in[4];   // [16,72]
  float* out = (float*)d_out;                // mean(131072) ++ var(131072)
  float* nr  = (float*)d_ws;                 // 147456 B

  gp_prep_kernel<<<dim3((NEU + 255) / 256), dim3(256), 0, stream>>>(z, h, rl, nr);

  dim3 grid(RTOT / 64, OC_N);                // (128, 16) = 2048 blocks
  dim3 block(64, 9);                         // 576 threads = 9 waves
  gp_fused_kernel<<<grid, block, 0, stream>>>(xm, xv, nr, out);
}